// Round 7
// baseline (720.367 us; speedup 1.0000x reference)
//
#include <hip/hip_runtime.h>
#include <hip/hip_bf16.h>
#include <math.h>

// Problem constants
#define B_   16
#define L_   196
#define FD_  2048
#define N_   1000
#define WD_  300
#define HD_  512
#define DD_  5
#define E_   50000
#define TMAX_ 5
#define NIMG_ 1000

typedef __attribute__((ext_vector_type(8))) short bf16x8;
typedef __attribute__((ext_vector_type(4))) float f32x4;

__device__ __forceinline__ short bf_hi(float x) {
    unsigned u = __float_as_uint(x);
    unsigned r = u + 0x7fffu + ((u >> 16) & 1u);
    return (short)(r >> 16);
}
__device__ __forceinline__ float bf2f_(short s) {
    return __uint_as_float(((unsigned)(unsigned short)s) << 16);
}

// ---------------------------------------------------------------------------
// fp32 -> bf16 hi/lo planes, elementwise (4 per thread)
// ---------------------------------------------------------------------------
__global__ void conv_split(const float* __restrict__ in, short* __restrict__ outH,
                           short* __restrict__ outL, int n4)
{
    int i = blockIdx.x * blockDim.x + threadIdx.x;
    if (i >= n4) return;
    float4 v = *(const float4*)(in + i * 4);
    float xs[4] = {v.x, v.y, v.z, v.w};
    short h[4], l[4];
    #pragma unroll
    for (int j = 0; j < 4; j++) {
        h[j] = bf_hi(xs[j]);
        if (outL) l[j] = bf_hi(xs[j] - bf2f_(h[j]));
    }
    *(int2*)(outH + i * 4) = *(int2*)h;
    if (outL) *(int2*)(outL + i * 4) = *(int2*)l;
}

// ---------------------------------------------------------------------------
// Transpose + convert: in fp32 [K][N] -> outH (and optionally outL) bf16 [N][K]
// ---------------------------------------------------------------------------
__global__ __launch_bounds__(256) void transconv(
    const float* __restrict__ in, short* __restrict__ outH, short* __restrict__ outL,
    int K, int N)
{
    __shared__ float tile[32][33];
    int k0 = blockIdx.x * 32, n0 = blockIdx.y * 32;
    int t = threadIdx.x;
    int tr = t >> 5, tc = t & 31;
    #pragma unroll
    for (int i = 0; i < 4; i++) {
        int k = k0 + tr + i * 8, n = n0 + tc;
        tile[tr + i * 8][tc] = (k < K && n < N) ? in[(long)k * N + n] : 0.f;
    }
    __syncthreads();
    #pragma unroll
    for (int i = 0; i < 4; i++) {
        int n = n0 + tr + i * 8, k = k0 + tc;
        if (n < N && k < K) {
            float x = tile[tc][tr + i * 8];
            short hi = bf_hi(x);
            outH[(long)n * K + k] = hi;
            if (outL) outL[(long)n * K + k] = bf_hi(x - bf2f_(hi));
        }
    }
}

// ---------------------------------------------------------------------------
// bounded 8-short load from a row pointer
// ---------------------------------------------------------------------------
__device__ __forceinline__ void load8s(const short* __restrict__ rowp, bool rowok,
                                       int gk, int K, short* tmp)
{
    if (rowok && gk + 8 <= K) {
        *(int2*)&tmp[0] = *(const int2*)(rowp + gk);
        *(int2*)&tmp[4] = *(const int2*)(rowp + gk + 4);
    } else {
        #pragma unroll
        for (int j = 0; j < 8; j++)
            tmp[j] = (rowok && gk + j < K) ? rowp[gk + j] : (short)0;
    }
}

// ---------------------------------------------------------------------------
// MFMA GEMM v3: C = act(A @ B^T + bias). A,B bf16 planes [rows][K] (hi +
// optional lo). Block tile 128x64, 256 threads = 4 waves, each wave 32x64
// (2 row-frags x 4 col-frags), BK=32, 16x16x32 bf16 MFMA.
// SPLIT: AhBh + AlBh + AhBl fused in-loop (24 MFMA vs 12 ds_read per k-step).
// OUT_KF1: fused keys+F1 epilogue -- col<512: keys hi/lo planes (+b_key);
//          col>=512: F1^T bf16 [b][512][196].
// ---------------------------------------------------------------------------
#define OUT_F32   0
#define OUT_SPLIT 1
#define OUT_BF16  3
#define OUT_KF1   4

template<int OUTMODE, bool SPLIT, bool RELU>
__global__ __launch_bounds__(256) void mm3(
    const short* __restrict__ Ah, const short* __restrict__ Al,
    const short* __restrict__ Bh, const short* __restrict__ Bl,
    const float* __restrict__ bias,
    void* __restrict__ C0, void* __restrict__ C1, void* __restrict__ C2,
    int M, int N, int K, long sA, long sB, long sC)
{
    __shared__ short AsH[128][40];
    __shared__ short AsL[SPLIT ? 128 : 1][40];
    __shared__ short BsH[64][40];
    __shared__ short BsL[SPLIT ? 64 : 1][40];
    int z = blockIdx.z;
    Ah += (long)z * sA;
    Bh += (long)z * sB;
    if (SPLIT) { Al += (long)z * sA; Bl += (long)z * sB; }
    int t = threadIdx.x;
    int lane = t & 63, w = t >> 6;
    int q = lane >> 4, r = lane & 15;
    int row0 = blockIdx.y * 128, col0 = blockIdx.x * 64;
    f32x4 zero4 = {0.f, 0.f, 0.f, 0.f};
    f32x4 acc[2][4];
    #pragma unroll
    for (int i = 0; i < 2; i++)
        #pragma unroll
        for (int j = 0; j < 4; j++) acc[i][j] = zero4;

    int arow = t >> 1, akc = (t & 1) * 16;   // A: 128 rows, 16 shorts each
    int brow = t >> 2, bkc = (t & 3) * 8;    // B: 64 rows, 8 shorts each
    int Ksteps = (K + 31) >> 5;
    for (int ks = 0; ks < Ksteps; ks++) {
        int k0 = ks * 32;
        short tmp[8];
        {
            int gm = row0 + arow;
            bool ok = gm < M;
            const short* ap = Ah + (long)gm * K;
            load8s(ap, ok, k0 + akc, K, tmp);
            *(int4*)&AsH[arow][akc] = *(int4*)tmp;
            load8s(ap, ok, k0 + akc + 8, K, tmp);
            *(int4*)&AsH[arow][akc + 8] = *(int4*)tmp;
            if (SPLIT) {
                const short* alp = Al + (long)gm * K;
                load8s(alp, ok, k0 + akc, K, tmp);
                *(int4*)&AsL[arow][akc] = *(int4*)tmp;
                load8s(alp, ok, k0 + akc + 8, K, tmp);
                *(int4*)&AsL[arow][akc + 8] = *(int4*)tmp;
            }
        }
        {
            int gn = col0 + brow;
            bool ok = gn < N;
            load8s(Bh + (long)gn * K, ok, k0 + bkc, K, tmp);
            *(int4*)&BsH[brow][bkc] = *(int4*)tmp;
            if (SPLIT) {
                load8s(Bl + (long)gn * K, ok, k0 + bkc, K, tmp);
                *(int4*)&BsL[brow][bkc] = *(int4*)tmp;
            }
        }
        __syncthreads();
        bf16x8 ah0 = *(const bf16x8*)&AsH[w * 32 + r][q * 8];
        bf16x8 ah1 = *(const bf16x8*)&AsH[w * 32 + 16 + r][q * 8];
        bf16x8 al0, al1;
        if (SPLIT) {
            al0 = *(const bf16x8*)&AsL[w * 32 + r][q * 8];
            al1 = *(const bf16x8*)&AsL[w * 32 + 16 + r][q * 8];
        }
        #pragma unroll
        for (int ct = 0; ct < 4; ct++) {
            bf16x8 bh = *(const bf16x8*)&BsH[ct * 16 + r][q * 8];
            acc[0][ct] = __builtin_amdgcn_mfma_f32_16x16x32_bf16(ah0, bh, acc[0][ct], 0, 0, 0);
            acc[1][ct] = __builtin_amdgcn_mfma_f32_16x16x32_bf16(ah1, bh, acc[1][ct], 0, 0, 0);
            if (SPLIT) {
                acc[0][ct] = __builtin_amdgcn_mfma_f32_16x16x32_bf16(al0, bh, acc[0][ct], 0, 0, 0);
                acc[1][ct] = __builtin_amdgcn_mfma_f32_16x16x32_bf16(al1, bh, acc[1][ct], 0, 0, 0);
                bf16x8 bl = *(const bf16x8*)&BsL[ct * 16 + r][q * 8];
                acc[0][ct] = __builtin_amdgcn_mfma_f32_16x16x32_bf16(ah0, bl, acc[0][ct], 0, 0, 0);
                acc[1][ct] = __builtin_amdgcn_mfma_f32_16x16x32_bf16(ah1, bl, acc[1][ct], 0, 0, 0);
            }
        }
        __syncthreads();
    }
    #pragma unroll
    for (int i = 0; i < 2; i++) {
        #pragma unroll
        for (int ct = 0; ct < 4; ct++) {
            #pragma unroll
            for (int reg = 0; reg < 4; reg++) {
                int m = row0 + w * 32 + i * 16 + q * 4 + reg;
                int n = col0 + ct * 16 + r;
                if (m >= M || n >= N) continue;
                float v = acc[i][ct][reg];
                if (OUTMODE == OUT_KF1) {
                    if (col0 < 512) {  // keys half (block-uniform)
                        float v2 = v + bias[n];
                        long idx = (long)m * 512 + n;
                        short hi = bf_hi(v2);
                        ((short*)C0)[idx] = hi;
                        ((short*)C1)[idx] = bf_hi(v2 - bf2f_(hi));
                    } else {           // F1 half -> transposed bf16 [b][512][196]
                        int b = m / 196, l = m - b * 196;
                        int nf = n - 512;
                        ((short*)C2)[((long)b * 512 + nf) * 196 + l] = bf_hi(v);
                    }
                } else {
                    if (bias) v += bias[n];
                    if (RELU) v = fmaxf(v, 0.f);
                    long idx = (long)z * sC + (long)m * N + n;
                    if (OUTMODE == OUT_F32) {
                        ((float*)C0)[idx] = v;
                    } else if (OUTMODE == OUT_SPLIT) {
                        short hi = bf_hi(v);
                        ((short*)C0)[idx] = hi;
                        ((short*)C1)[idx] = bf_hi(v - bf2f_(hi));
                    } else { // OUT_BF16
                        ((short*)C0)[idx] = bf_hi(v);
                    }
                }
            }
        }
    }
}

// ---------------------------------------------------------------------------
// Edge MLP via MFMA: 64 edges x 256 units/block, K=600.
// ---------------------------------------------------------------------------
__global__ __launch_bounds__(256) void edge_mfma(
    const short* __restrict__ embedH, const int* __restrict__ edges,
    const short* __restrict__ Wr1T, const float* __restrict__ br1,
    const float* __restrict__ Wr2, const float* __restrict__ br2,
    float* __restrict__ prop)
{
    __shared__ short As[64][40];
    __shared__ short Bs[256][40];
    __shared__ int src[64], dst[64];
    __shared__ float part[64][5];
    int t = threadIdx.x;
    int e0 = blockIdx.x * 64;
    if (t < 64) {
        int e = e0 + t;
        src[t] = (e < E_) ? edges[e] : 0;
        dst[t] = (e < E_) ? edges[E_ + e] : 0;
    }
    __syncthreads();
    int lane = t & 63, w = t >> 6, q = lane >> 4, r = lane & 15;
    f32x4 zero4 = {0.f, 0.f, 0.f, 0.f};
    f32x4 acc[4][4];
    #pragma unroll
    for (int i = 0; i < 4; i++)
        #pragma unroll
        for (int j = 0; j < 4; j++) acc[i][j] = zero4;

    for (int ks = 0; ks < 19; ks++) {
        int k0 = ks * 32;
        {
            int arow = t >> 2, kc = (t & 3) * 8;
            int gk0 = k0 + kc;
            int sn = src[arow], dn = dst[arow];
            short tmp[8];
            if (gk0 + 8 <= 300) {
                const short* p = embedH + (long)sn * 300 + gk0;
                *(int2*)&tmp[0] = *(const int2*)p;
                *(int2*)&tmp[4] = *(const int2*)(p + 4);
            } else if (gk0 >= 300 && gk0 + 8 <= 600) {
                const short* p = embedH + (long)dn * 300 + (gk0 - 300);
                *(int2*)&tmp[0] = *(const int2*)p;
                *(int2*)&tmp[4] = *(const int2*)(p + 4);
            } else {
                #pragma unroll
                for (int j = 0; j < 8; j++) {
                    int gk = gk0 + j;
                    short v = 0;
                    if (gk < 300) v = embedH[(long)sn * 300 + gk];
                    else if (gk < 600) v = embedH[(long)dn * 300 + gk - 300];
                    tmp[j] = v;
                }
            }
            *(int4*)&As[arow][kc] = *(int4*)&tmp[0];
        }
        #pragma unroll
        for (int i = 0; i < 4; i++) {
            int n = i * 64 + (t >> 2), kc = (t & 3) * 8;
            int gk0 = k0 + kc;
            short tmp[8];
            if (gk0 + 8 <= 600) {
                const short* p = Wr1T + (long)n * 600 + gk0;
                *(int2*)&tmp[0] = *(const int2*)p;
                *(int2*)&tmp[4] = *(const int2*)(p + 4);
            } else {
                #pragma unroll
                for (int j = 0; j < 8; j++) tmp[j] = 0;
            }
            *(int4*)&Bs[n][kc] = *(int4*)&tmp[0];
        }
        __syncthreads();
        bf16x8 af[4], bfr[4];
        #pragma unroll
        for (int rt = 0; rt < 4; rt++) af[rt] = *(const bf16x8*)&As[rt * 16 + r][q * 8];
        #pragma unroll
        for (int ct = 0; ct < 4; ct++) bfr[ct] = *(const bf16x8*)&Bs[w * 64 + ct * 16 + r][q * 8];
        #pragma unroll
        for (int rt = 0; rt < 4; rt++)
            #pragma unroll
            for (int ct = 0; ct < 4; ct++)
                acc[rt][ct] = __builtin_amdgcn_mfma_f32_16x16x32_bf16(af[rt], bfr[ct], acc[rt][ct], 0, 0, 0);
        __syncthreads();
    }
    float b1v[4], w2v[4];
    #pragma unroll
    for (int ct = 0; ct < 4; ct++) {
        int u = w * 64 + ct * 16 + r;
        b1v[ct] = br1[u];
        w2v[ct] = Wr2[u];
    }
    #pragma unroll
    for (int rt = 0; rt < 4; rt++) {
        #pragma unroll
        for (int reg = 0; reg < 4; reg++) {
            float s = 0.f;
            #pragma unroll
            for (int ct = 0; ct < 4; ct++)
                s = fmaf(fmaxf(acc[rt][ct][reg] + b1v[ct], 0.f), w2v[ct], s);
            s += __shfl_xor(s, 1);
            s += __shfl_xor(s, 2);
            s += __shfl_xor(s, 4);
            s += __shfl_xor(s, 8);
            if (r == 0) part[rt * 16 + q * 4 + reg][w] = s;
        }
    }
    __syncthreads();
    if (t < 64 && e0 + t < E_) {
        float s = part[t][0] + part[t][1] + part[t][2] + part[t][3];
        atomicAdd(&prop[(long)src[t] * N_ + dst[t]], tanhf(s + br2[0]));
    }
}

// ---------------------------------------------------------------------------
__global__ void pooled_kernel(const float* __restrict__ feats, float* __restrict__ pooled)
{
    int idx = blockIdx.x * blockDim.x + threadIdx.x;
    if (idx >= B_ * FD_) return;
    int b = idx / FD_, f = idx % FD_;
    const float* p = feats + (long)b * L_ * FD_ + f;
    float acc = 0.f;
    for (int l = 0; l < L_; l++) acc += p[(long)l * FD_];
    pooled[idx] = acc * (1.0f / L_);
}

__global__ void clf_partial(const float* __restrict__ pooled, const float* __restrict__ W,
                            const float* __restrict__ bias, float* __restrict__ out)
{
    int i = blockIdx.x * blockDim.x + threadIdx.x;
    int ks = blockIdx.y;
    if (i >= B_ * NIMG_) return;
    int b = i / NIMG_, n = i % NIMG_;
    const float* p = pooled + (long)b * FD_ + ks * 256;
    const float* w = W + (long)(ks * 256) * NIMG_ + n;
    float acc = (ks == 0) ? bias[n] : 0.f;
    #pragma unroll 4
    for (int k = 0; k < 256; k++) acc = fmaf(p[k], w[(long)k * NIMG_], acc);
    atomicAdd(&out[i], acc);
}

// in-place row softmax; optional bf16 copy of the result
template<int NCOLS>
__global__ void softmax_rows(float* __restrict__ X, short* __restrict__ Xb, int rows)
{
    int gid = blockIdx.x * blockDim.x + threadIdx.x;
    int wave = gid >> 6, lane = gid & 63;
    if (wave >= rows) return;
    float* row = X + (long)wave * NCOLS;
    const int PER = (NCOLS + 63) / 64;
    float v[PER];
    float m = -1e30f;
    int cnt = 0;
    for (int k = lane; k < NCOLS; k += 64) { v[cnt] = row[k]; m = fmaxf(m, v[cnt]); cnt++; }
    #pragma unroll
    for (int off = 32; off; off >>= 1) m = fmaxf(m, __shfl_xor(m, off));
    float s = 0.f;
    for (int i = 0; i < cnt; i++) { v[i] = expf(v[i] - m); s += v[i]; }
    #pragma unroll
    for (int off = 32; off; off >>= 1) s += __shfl_xor(s, off);
    float inv = 1.f / s;
    cnt = 0;
    for (int k = lane; k < NCOLS; k += 64) {
        float val = v[cnt++] * inv;
        row[k] = val;
        if (Xb) Xb[(long)wave * NCOLS + k] = bf_hi(val);
    }
}

// h0: reads h1 (bf16 [r][512]), writes transposed [N][B][D]
__global__ void h0_kernel(const short* __restrict__ h1, const float* __restrict__ Wf2,
                          const float* __restrict__ bf2, float* __restrict__ h0t, int rows)
{
    int gid = blockIdx.x * blockDim.x + threadIdx.x;
    int wave = gid >> 6, lane = gid & 63;
    if (wave >= rows) return;
    const short* row = h1 + (long)wave * HD_;
    float acc[DD_] = {};
    for (int k = lane; k < HD_; k += 64) {
        float v = bf2f_(row[k]);
        #pragma unroll
        for (int d = 0; d < DD_; d++) acc[d] = fmaf(v, Wf2[k * DD_ + d], acc[d]);
    }
    #pragma unroll
    for (int d = 0; d < DD_; d++)
        #pragma unroll
        for (int off = 32; off; off >>= 1) acc[d] += __shfl_down(acc[d], off);
    if (lane == 0) {
        int b = wave / N_, n = wave % N_;
        #pragma unroll
        for (int d = 0; d < DD_; d++)
            h0t[(long)n * (B_ * DD_) + b * DD_ + d] = acc[d] + bf2[d];
    }
}

__global__ void zero_kernel(float* __restrict__ p, int n)
{
    int i = blockIdx.x * blockDim.x + threadIdx.x;
    if (i < n) p[i] = 0.f;
}

// ---------------------------------------------------------------------------
// Recurrence step, one thread per output element (H [N][B*D=80]).
// ---------------------------------------------------------------------------
__global__ __launch_bounds__(320) void step_kernel(
    const float* __restrict__ prop, const float* __restrict__ Hin,
    float* __restrict__ Hout,
    const float* __restrict__ W_ih, const float* __restrict__ b_ih,
    const float* __restrict__ W_hh, const float* __restrict__ b_hh)
{
    __shared__ float msg[4][80];
    int t = threadIdx.x;
    int nl = t / 80, c = t - nl * 80;
    int n = blockIdx.x * 4 + nl;
    const float* pr = prop + (long)n * N_;
    const float* hc = Hin + c;
    float acc = 0.f;
    #pragma unroll 4
    for (int m4 = 0; m4 < N_; m4 += 4) {
        float4 pv = *(const float4*)(pr + m4);
        acc = fmaf(pv.x, hc[(long)(m4 + 0) * 80], acc);
        acc = fmaf(pv.y, hc[(long)(m4 + 1) * 80], acc);
        acc = fmaf(pv.z, hc[(long)(m4 + 2) * 80], acc);
        acc = fmaf(pv.w, hc[(long)(m4 + 3) * 80], acc);
    }
    msg[nl][c] = tanhf(acc);
    __syncthreads();
    if (t < 64) {
        int nl2 = t >> 4, b = t & 15;
        int n2 = blockIdx.x * 4 + nl2;
        float xv[DD_], h[DD_];
        #pragma unroll
        for (int j = 0; j < DD_; j++) {
            xv[j] = msg[nl2][b * DD_ + j];
            h[j] = Hin[(long)n2 * 80 + b * DD_ + j];
        }
        float gi[3 * DD_], gh[3 * DD_];
        #pragma unroll
        for (int g = 0; g < 3 * DD_; g++) {
            float a = b_ih[g], cc = b_hh[g];
            #pragma unroll
            for (int k = 0; k < DD_; k++) {
                a = fmaf(xv[k], W_ih[g * DD_ + k], a);
                cc = fmaf(h[k], W_hh[g * DD_ + k], cc);
            }
            gi[g] = a; gh[g] = cc;
        }
        #pragma unroll
        for (int j = 0; j < DD_; j++) {
            float rr = 1.f / (1.f + expf(-(gi[j] + gh[j])));
            float zz = 1.f / (1.f + expf(-(gi[DD_ + j] + gh[DD_ + j])));
            float nn2 = tanhf(gi[2 * DD_ + j] + rr * gh[2 * DD_ + j]);
            Hout[(long)n2 * 80 + b * DD_ + j] = (1.f - zz) * nn2 + zz * h[j];
        }
    }
}

__global__ void out_kernel(const float* __restrict__ ht, const float* __restrict__ Wo1,
                           const float* __restrict__ bo1, const float* __restrict__ Wo2,
                           const float* __restrict__ bo2, float* __restrict__ logits, int rows)
{
    int gid = blockIdx.x * blockDim.x + threadIdx.x;
    int wave = gid >> 6, lane = gid & 63;
    if (wave >= rows) return;
    int b = wave / N_, n = wave % N_;
    float x[DD_];
    #pragma unroll
    for (int i = 0; i < DD_; i++) x[i] = ht[(long)n * (B_ * DD_) + b * DD_ + i];
    float acc = 0.f;
    for (int j = lane; j < HD_; j += 64) {
        float h = bo1[j];
        #pragma unroll
        for (int d = 0; d < DD_; d++) h = fmaf(x[d], Wo1[d * HD_ + j], h);
        h = fmaxf(h, 0.f);
        acc = fmaf(h, Wo2[j], acc);
    }
    #pragma unroll
    for (int off = 32; off; off >>= 1) acc += __shfl_down(acc, off);
    if (lane == 0) logits[wave] = acc + bo2[0];
}

// ---------------------------------------------------------------------------
extern "C" void kernel_launch(void* const* d_in, const int* in_sizes, int n_in,
                              void* d_out, int out_size, void* d_ws, size_t ws_size,
                              hipStream_t stream)
{
    const float* feats   = (const float*)d_in[0];
    const float* embed   = (const float*)d_in[1];
    const int*   edges   = (const int*)  d_in[2];
    const float* W_key   = (const float*)d_in[3];
    const float* b_key   = (const float*)d_in[4];
    const float* W_query = (const float*)d_in[5];
    const float* b_query = (const float*)d_in[6];
    const float* Wf1     = (const float*)d_in[7];
    const float* bf1     = (const float*)d_in[8];
    const float* Wf2     = (const float*)d_in[9];
    const float* bf2     = (const float*)d_in[10];
    const float* Wr1     = (const float*)d_in[11];
    const float* br1     = (const float*)d_in[12];
    const float* Wr2     = (const float*)d_in[13];
    const float* br2     = (const float*)d_in[14];
    const float* Wo1     = (const float*)d_in[15];
    const float* bo1     = (const float*)d_in[16];
    const float* Wo2     = (const float*)d_in[17];
    const float* bo2     = (const float*)d_in[18];
    const float* W_ih    = (const float*)d_in[19];
    const float* b_ih    = (const float*)d_in[20];
    const float* W_hh    = (const float*)d_in[21];
    const float* b_hh    = (const float*)d_in[22];
    const float* W_clf   = (const float*)d_in[23];
    const float* b_clf   = (const float*)d_in[24];

    float* out_logits = (float*)d_out;
    float* out_attn   = out_logits + B_ * N_;
    float* out_img    = out_attn + (long)B_ * N_ * L_;

    char* p = (char*)d_ws;
    auto alloc = [&](size_t bytes) { void* r = (void*)p; p += (bytes + 255) & ~(size_t)255; return r; };
    float* pooled  = (float*)alloc((size_t)B_ * FD_ * 4);
    short* featsH  = (short*)alloc((size_t)B_ * L_ * FD_ * 2);
    short* featsL  = (short*)alloc((size_t)B_ * L_ * FD_ * 2);
    short* WkfH    = (short*)alloc((size_t)1024 * FD_ * 2);   // rows 0..511 W_key^T, 512..1023 Wf1^T
    short* WkfL    = (short*)alloc((size_t)1024 * FD_ * 2);
    short* WqTh    = (short*)alloc((size_t)HD_ * WD_ * 2);
    short* WqTl    = (short*)alloc((size_t)HD_ * WD_ * 2);
    short* Wr1T    = (short*)alloc((size_t)256 * 600 * 2);
    short* embH    = (short*)alloc((size_t)N_ * WD_ * 2);
    short* embL    = (short*)alloc((size_t)N_ * WD_ * 2);
    short* keysH   = (short*)alloc((size_t)B_ * L_ * HD_ * 2);
    short* keysL   = (short*)alloc((size_t)B_ * L_ * HD_ * 2);
    short* qH      = (short*)alloc((size_t)N_ * HD_ * 2);
    short* qL      = (short*)alloc((size_t)N_ * HD_ * 2);
    short* attnH   = (short*)alloc((size_t)B_ * N_ * L_ * 2);
    short* F1T     = (short*)alloc((size_t)B_ * HD_ * L_ * 2);
    short* h1b     = (short*)alloc((size_t)B_ * N_ * HD_ * 2);
    float* prop    = (float*)alloc((size_t)N_ * N_ * 4);
    float* Ht0     = (float*)alloc((size_t)N_ * B_ * DD_ * 4);
    float* Ht1     = (float*)alloc((size_t)N_ * B_ * DD_ * 4);

    // --- imagenet classifier path ---
    pooled_kernel<<<(B_ * FD_ + 255) / 256, 256, 0, stream>>>(feats, pooled);
    zero_kernel<<<(B_ * NIMG_ + 255) / 256, 256, 0, stream>>>(out_img, B_ * NIMG_);
    {
        dim3 g((B_ * NIMG_ + 255) / 256, FD_ / 256);
        clf_partial<<<g, 256, 0, stream>>>(pooled, W_clf, b_clf, out_img);
    }
    softmax_rows<NIMG_><<<(B_ * 64 + 255) / 256, 256, 0, stream>>>(out_img, nullptr, B_);

    // --- operand pre-conversion ---
    {
        int n4 = B_ * L_ * FD_ / 4;
        conv_split<<<(n4 + 255) / 256, 256, 0, stream>>>(feats, featsH, featsL, n4);
    }
    {
        int n4 = N_ * WD_ / 4;
        conv_split<<<(n4 + 255) / 256, 256, 0, stream>>>(embed, embH, embL, n4);
    }
    {
        dim3 g((FD_ + 31) / 32, (HD_ + 31) / 32);
        transconv<<<g, 256, 0, stream>>>(W_key, WkfH, WkfL, FD_, HD_);
        transconv<<<g, 256, 0, stream>>>(Wf1, WkfH + (size_t)512 * FD_,
                                         WkfL + (size_t)512 * FD_, FD_, HD_);
    }
    {
        dim3 g((WD_ + 31) / 32, (HD_ + 31) / 32);
        transconv<<<g, 256, 0, stream>>>(W_query, WqTh, WqTl, WD_, HD_);
    }
    {
        dim3 g((600 + 31) / 32, (256 + 31) / 32);
        transconv<<<g, 256, 0, stream>>>(Wr1, Wr1T, nullptr, 600, 256);
    }

    // --- prop matrix ---
    zero_kernel<<<(N_ * N_ + 255) / 256, 256, 0, stream>>>(prop, N_ * N_);
    edge_mfma<<<(E_ + 63) / 64, 256, 0, stream>>>(embH, edges, Wr1T, br1, Wr2, br2, prop);

    // --- attention path ---
    // fused keys+F1: feats @ [W_key | Wf1] with split precision
    {
        dim3 g(1024 / 64, (B_ * L_ + 127) / 128, 1);
        mm3<OUT_KF1, true, false><<<g, 256, 0, stream>>>(
            featsH, featsL, WkfH, WkfL, b_key, keysH, keysL, F1T,
            B_ * L_, 1024, FD_, 0, 0, 0);
    }
    // queries = embed @ W_query + b_query -> hi/lo planes [1000][512]
    {
        dim3 g(HD_ / 64, (N_ + 127) / 128, 1);
        mm3<OUT_SPLIT, true, false><<<g, 256, 0, stream>>>(
            embH, embL, WqTh, WqTl, b_query, qH, qL, nullptr, N_, HD_, WD_, 0, 0, 0);
    }
    // scores[b] = queries @ keys[b]^T -> fp32 out_attn [b][1000][196]
    {
        dim3 g((L_ + 63) / 64, (N_ + 127) / 128, B_);
        mm3<OUT_F32, true, false><<<g, 256, 0, stream>>>(
            qH, qL, keysH, keysL, nullptr, out_attn, nullptr, nullptr, N_, L_, HD_,
            0, (long)L_ * HD_, (long)N_ * L_);
    }
    // softmax over 196, also emits bf16 copy for h1's A operand
    softmax_rows<L_><<<(B_ * N_ * 64 + 255) / 256, 256, 0, stream>>>(out_attn, attnH, B_ * N_);

    // h1 = relu(attn @ F1 + bf1) -> bf16 [b][1000][512]
    {
        dim3 g(HD_ / 64, (N_ + 127) / 128, B_);
        mm3<OUT_BF16, false, true><<<g, 256, 0, stream>>>(
            attnH, nullptr, F1T, nullptr, bf1, h1b, nullptr, nullptr, N_, HD_, L_,
            (long)N_ * L_, (long)HD_ * L_, (long)N_ * HD_);
    }
    // hidden (transposed [N][B][D]) = h1 @ Wf2 + bf2
    h0_kernel<<<(B_ * N_ * 64 + 255) / 256, 256, 0, stream>>>(h1b, Wf2, bf2, Ht0, B_ * N_);

    // --- recurrence: 5 fused steps, ping-pong ---
    {
        float* hin = Ht0;
        float* hout = Ht1;
        for (int step = 0; step < TMAX_; step++) {
            step_kernel<<<N_ / 4, 320, 0, stream>>>(prop, hin, hout,
                                                    W_ih, b_ih, W_hh, b_hh);
            float* tmp = hin; hin = hout; hout = tmp;
        }
        out_kernel<<<(B_ * N_ * 64 + 255) / 256, 256, 0, stream>>>(hin, Wo1, bo1, Wo2, bo2,
                                                                   out_logits, B_ * N_);
    }
}